// Round 1
// baseline (1098.806 us; speedup 1.0000x reference)
//
#include <hip/hip_runtime.h>

// MaxUnpooling2D scatter-add.
// updates: [32,64,64,128] f32, mask: same shape int32, values in [0, 128*128*128).
// out: [32,128,128,128] f32, out[b, m/(128*128), (m/128)%128, c] += upd[b,h,w,c].
// Key identity: out flat index = (b<<21) + (m & ~127) + c   (no divides).
//   c = in_flat & 127, b = in_flat >> 19 (since H*W*C = 64*64*128 = 2^19).

__global__ __launch_bounds__(256) void unpool_scatter(
    const float4* __restrict__ upd, const int4* __restrict__ mask,
    float* __restrict__ out, int n4)
{
    int i = blockIdx.x * blockDim.x + threadIdx.x;
    if (i >= n4) return;

    float4 u = upd[i];
    int4  m = mask[i];

    int base = i << 2;            // flat element index of .x
    int c0   = base & 127;        // channel of .x (c0..c0+3 same (b,h,w): 4 | 128)
    int b    = base >> 19;        // batch
    float* o = out + ((long)b << 21) + c0;

    atomicAdd(o + (m.x & 0x7FFFFF80)    , u.x);
    atomicAdd(o + (m.y & 0x7FFFFF80) + 1, u.y);
    atomicAdd(o + (m.z & 0x7FFFFF80) + 2, u.z);
    atomicAdd(o + (m.w & 0x7FFFFF80) + 3, u.w);
}

extern "C" void kernel_launch(void* const* d_in, const int* in_sizes, int n_in,
                              void* d_out, int out_size, void* d_ws, size_t ws_size,
                              hipStream_t stream) {
    const float* upd  = (const float*)d_in[0];
    const int*   mask = (const int*)d_in[1];
    float*       out  = (float*)d_out;

    // Output is re-poisoned to 0xAA before every launch — zero it.
    hipMemsetAsync(d_out, 0, (size_t)out_size * sizeof(float), stream);

    int n  = in_sizes[0];       // 16,777,216
    int n4 = n >> 2;            // 4,194,304 float4/int4 groups
    int blocks = (n4 + 255) / 256;
    unpool_scatter<<<blocks, 256, 0, stream>>>(
        (const float4*)upd, (const int4*)mask, out, n4);
}

// Round 2
// 750.444 us; speedup vs baseline: 1.4642x; 1.4642x over previous
//
#include <hip/hip_runtime.h>

// MaxUnpooling2D scatter-add, privatized per (b,c) output plane.
// updates/mask: [32,64,64,128], out: [32,128,128,128] f32.
// mask m in [0, 2^21); out[b, m>>14, (m>>7)&127, c] += upd[b,h,w,c].
// Plane bin for fixed (b,c): (y,x) = m >> 7  (14 bits -> 16384 bins = 64 KiB f32).
// Each (b,c) plane is owned by exactly one workgroup -> LDS atomics only,
// plain stores to global, no output zeroing needed (every element written).
//
// blockIdx swizzle: the 16 workgroups covering channels [16k,16k+16) of one
// batch share every 64B input/output cache line (layout is channel-last).
// XCD assignment ~ blockIdx % 8, so we arrange those 16 blocks to have equal
// blockIdx mod 8 and adjacent dispatch order -> line reuse in one XCD's L2,
// and their 4B-dirty output stores merge into full-line writebacks.

#define HWC (64 * 64 * 128)   // 2^19 elements per batch (input)
#define PLANE 16384           // 128*128 bins per (b,c) plane

__global__ __launch_bounds__(256, 2) void unpool_plane(
    const float* __restrict__ upd, const int* __restrict__ mask,
    float* __restrict__ out)
{
    __shared__ float plane[PLANE];   // 64 KiB -> 2 blocks/CU

    // blockIdx -> (b, c):  bid = span*128 + cLo*8 + r ;  g = span*8 + r
    // b = g>>3, c = (g&7)*16 + cLo.  All 16 cLo blocks of a group share r.
    int bid    = blockIdx.x;
    int span   = bid >> 7;
    int within = bid & 127;
    int r      = within & 7;
    int cLo    = within >> 3;
    int g      = span * 8 + r;
    int b      = g >> 3;
    int c      = (g & 7) * 16 + cLo;

    int t = threadIdx.x;

    // zero the LDS plane (float4 x 16 per thread)
    float4* p4 = (float4*)plane;
    #pragma unroll
    for (int k = 0; k < 16; ++k)
        p4[t + k * 256] = make_float4(0.f, 0.f, 0.f, 0.f);
    __syncthreads();

    // gather this plane's 4096 inputs (stride 128 floats) + LDS accumulate
    const float* ub = upd  + (size_t)b * HWC + c;
    const int*   mb = mask + (size_t)b * HWC + c;
    #pragma unroll
    for (int k = 0; k < 16; ++k) {
        int pos = t + k * 256;                 // (h,w) position 0..4095
        float u = ub[(size_t)pos * 128];
        int   m = mb[(size_t)pos * 128];
        atomicAdd(&plane[m >> 7], u);          // ds_add_f32, no return
    }
    __syncthreads();

    // write the plane: out[b, y, x, c], stride 128 floats
    float* ob = out + ((size_t)b << 21) + c;
    #pragma unroll
    for (int k = 0; k < 64; ++k) {
        int p = t + k * 256;
        ob[(size_t)p * 128] = plane[p];
    }
}

extern "C" void kernel_launch(void* const* d_in, const int* in_sizes, int n_in,
                              void* d_out, int out_size, void* d_ws, size_t ws_size,
                              hipStream_t stream) {
    const float* upd  = (const float*)d_in[0];
    const int*   mask = (const int*)d_in[1];
    float*       out  = (float*)d_out;

    // 32 batches * 128 channels = 4096 plane-workgroups; no memset needed.
    unpool_plane<<<4096, 256, 0, stream>>>(upd, mask, out);
}